// Round 5
// baseline (193.262 us; speedup 1.0000x reference)
//
#include <hip/hip_runtime.h>

typedef unsigned short u16;
typedef unsigned int u32;
typedef unsigned long long u64;

using bf16x8 = __bf16 __attribute__((ext_vector_type(8)));
using f32x4  = float  __attribute__((ext_vector_type(4)));

#define LDS_SPACE __attribute__((address_space(3)))
#define GLB_SPACE __attribute__((address_space(1)))

static __device__ __forceinline__ u16 f2bf(float f) {
  union { float f; u32 u; } c; c.f = f;
  u32 u = c.u;
  return (u16)((u + 0x7fffu + ((u >> 16) & 1u)) >> 16);   // RNE
}
static __device__ __forceinline__ float bf2f(u16 u) {
  union { u32 u; float f; } c; c.u = ((u32)u) << 16;
  return c.f;
}

static __device__ __forceinline__ void fence_barrier() {
  asm volatile("" ::: "memory");
  __builtin_amdgcn_s_barrier();
  asm volatile("" ::: "memory");
}

// ---------------- f32 -> bf16 convert (x) ----------------
__global__ __launch_bounds__(256) void cvt_f32_bf16_k(const float* __restrict__ src,
                                                      u16* __restrict__ dst, int n4) {
  int i = blockIdx.x * 256 + threadIdx.x;
  if (i >= n4) return;
  float4 v = ((const float4*)src)[i];
  ushort4 o;
  o.x = f2bf(v.x); o.y = f2bf(v.y); o.z = f2bf(v.z); o.w = f2bf(v.w);
  ((ushort4*)dst)[i] = o;
}

// ---------------- transpose + convert (weights) ----------------
__global__ __launch_bounds__(256) void transpose_cvt_k(const float* __restrict__ src,
                                                       u16* __restrict__ dst, int R, int C) {
  __shared__ float t[32][33];
  int lx = threadIdx.x & 31, ly = threadIdx.x >> 5;
  int r0 = blockIdx.y * 32, c0 = blockIdx.x * 32;
  #pragma unroll
  for (int i = 0; i < 32; i += 8)
    t[ly + i][lx] = src[(size_t)(r0 + ly + i) * C + c0 + lx];
  __syncthreads();
  #pragma unroll
  for (int i = 0; i < 32; i += 8)
    dst[(size_t)(c0 + ly + i) * R + r0 + lx] = f2bf(t[lx][ly + i]);
}

// ---------------- bf16 transpose of V region of Y -> Vt [512][2048] ---------
__global__ __launch_bounds__(256) void vtrans_k(const u16* __restrict__ Y,
                                                u16* __restrict__ Vt) {
  __shared__ u16 t[64][72];
  const int s0 = blockIdx.x * 64;
  const int c0 = blockIdx.y * 64;
  const int lx = threadIdx.x & 63, ly = threadIdx.x >> 6;
  #pragma unroll
  for (int i = 0; i < 64; i += 4)
    t[i + ly][lx] = Y[(size_t)(s0 + i + ly) * 3072 + 2560 + c0 + lx];
  __syncthreads();
  #pragma unroll
  for (int i = 0; i < 64; i += 4)
    Vt[(size_t)(c0 + i + ly) * 2048 + s0 + lx] = t[lx][i + ly];
}

// ------- GEMM: C[M][N] = A[M][K]*Bt[N][K]^T, BM=64 BN=128 (2-phase dbuf) ----
template <typename OutT>
__global__ __launch_bounds__(256) void gemm64_k(const u16* __restrict__ A,
                                                const u16* __restrict__ Bt,
                                                OutT* __restrict__ C,
                                                int M, int N, int K) {
  __shared__ u16 As[2][64 * 32];
  __shared__ u16 Bs[2][128 * 32];
  const int tid = threadIdx.x, lane = tid & 63, wave = tid >> 6;
  const int wr = wave >> 1, wc = wave & 1;
  const int bm = blockIdx.y, bn = blockIdx.x;
  const int l15 = lane & 15, lq = lane >> 4;
  f32x4 acc[2][4] = {};

  const int srow = lane >> 2;
  const int scol = (lane & 3) * 8;
  const u16* Ag = A + (size_t)(bm * 64 + wave * 16 + srow) * K + scol;
  const u16* Bg = Bt + (size_t)(bn * 128 + wave * 32 + srow) * K + scol;

  auto stage = [&](int buf, int k0) {
    __builtin_amdgcn_global_load_lds((const GLB_SPACE u32*)(Ag + k0),
                                     (LDS_SPACE u32*)&As[buf][wave * 512], 16, 0, 0);
    #pragma unroll
    for (int i = 0; i < 2; ++i)
      __builtin_amdgcn_global_load_lds((const GLB_SPACE u32*)(Bg + k0 + (size_t)i * 16 * K),
                                       (LDS_SPACE u32*)&Bs[buf][wave * 1024 + i * 512], 16, 0, 0);
  };

  stage(0, 0);
  for (int k0 = 0; k0 < K; k0 += 32) {
    const int cur = (k0 >> 5) & 1;
    fence_barrier();
    if (k0 + 32 < K) {
      stage(cur ^ 1, k0 + 32);
      asm volatile("s_waitcnt vmcnt(3)" ::: "memory");
    } else {
      asm volatile("s_waitcnt vmcnt(0)" ::: "memory");
    }
    fence_barrier();

    bf16x8 a[2], b[4];
    const u16* ap = &As[cur][(wr * 32 + l15) * 32 + lq * 8];
    const u16* bp = &Bs[cur][(wc * 64 + l15) * 32 + lq * 8];
    #pragma unroll
    for (int m = 0; m < 2; ++m) a[m] = *(const bf16x8*)(ap + m * 16 * 32);
    #pragma unroll
    for (int n = 0; n < 4; ++n) b[n] = *(const bf16x8*)(bp + n * 16 * 32);
    #pragma unroll
    for (int m = 0; m < 2; ++m)
      #pragma unroll
      for (int n = 0; n < 4; ++n)
        acc[m][n] = __builtin_amdgcn_mfma_f32_16x16x32_bf16(a[m], b[n], acc[m][n], 0, 0, 0);
  }

  const int r0 = bm * 64 + wr * 32 + lq * 4;
  const int c0 = bn * 128 + wc * 64 + l15;
  #pragma unroll
  for (int m = 0; m < 2; ++m)
    #pragma unroll
    for (int n = 0; n < 4; ++n)
      #pragma unroll
      for (int r = 0; r < 4; ++r) {
        float v = acc[m][n][r];
        size_t off = (size_t)(r0 + m * 16 + r) * N + (c0 + n * 16);
        if constexpr (sizeof(OutT) == 2) ((u16*)C)[off] = f2bf(v);
        else C[off] = v;
      }
}

// ---------------- RoPE on Q (cols 0..2047) and K (cols 2048..2559) of Y ------
__global__ __launch_bounds__(256) void rope_k(u16* __restrict__ Y,
                                              const float* __restrict__ freq) {
  int idx = blockIdx.x * 256 + threadIdx.x;
  int s = idx / 1280;
  int rem = idx - s * 1280;
  int h = rem >> 5;
  int i = rem & 31;
  int col = (h < 32) ? (h * 64 + 2 * i) : (2048 + (h - 32) * 64 + 2 * i);
  float ang = freq[s * 32 + i];
  float sn, cs;
  sincosf(ang, &sn, &cs);
  size_t base = (size_t)s * 3072 + col;
  float e = bf2f(Y[base]), o = bf2f(Y[base + 1]);
  Y[base]     = f2bf(e * cs - o * sn);
  Y[base + 1] = f2bf(e * sn + o * cs);
}

// ---------------- Flash attention: causal GQA, pinned 3-stage pipeline -------
// One wave per block; 32 q-rows per wave; K/V direct from L2.
// Pipeline: K(t+2) issued right after QK^T(t) frees its buffer (2-tile lead);
// V(t+1) issued right after PV(t) (1-tile lead); one vmcnt(8) per tile.
__global__ __launch_bounds__(64, 2) void attn_k(const u16* __restrict__ Y,
                                                const u16* __restrict__ Vtg,
                                                u16* __restrict__ Out) {
  __shared__ u32 Ps[2][16 * 36];
  const int bx = blockIdx.x;
  const int qh = bx & 31;
  const int ws = 63 - (bx >> 5);              // big tiles dispatched first
  const int kvh = qh >> 2;
  const int q0w = ws * 32;
  const int ntiles = (q0w >> 6) + 1;
  const int lane = threadIdx.x & 63;
  const int l15 = lane & 15, lq = lane >> 4;

  bf16x8 qf[2][2];
  #pragma unroll
  for (int qs = 0; qs < 2; ++qs)
    #pragma unroll
    for (int kk = 0; kk < 2; ++kk)
      qf[qs][kk] = *(const bf16x8*)&Y[(size_t)(q0w + qs * 16 + l15) * 3072 +
                                      qh * 64 + kk * 32 + lq * 8];

  float m_[2] = { -INFINITY, -INFINITY };
  float l_[2] = { 0.f, 0.f };                 // per-lane partial sums
  f32x4 accO[2][4] = {};
  constexpr float SC = 0.18033688011112042f;  // log2(e)/8

  const u16* Kg = Y + 2048 + kvh * 64 + (size_t)l15 * 3072 + lq * 8;
  const u16* Vg = Vtg + (size_t)(kvh * 64 + l15) * 2048 + lq * 8;

  bf16x8 kfA[2][4], kfB[2][4], vf[4][2];

  auto issueK = [&](bf16x8 (&kf)[2][4], int t0) {
    #pragma unroll
    for (int kt = 0; kt < 4; ++kt)
      #pragma unroll
      for (int kk = 0; kk < 2; ++kk)
        kf[kk][kt] = *(const bf16x8*)&Kg[(size_t)(t0 + kt * 16) * 3072 + kk * 32];
  };
  auto issueV = [&](int t0) {
    #pragma unroll
    for (int dt = 0; dt < 4; ++dt)
      #pragma unroll
      for (int c = 0; c < 2; ++c)
        vf[dt][c] = *(const bf16x8*)&Vg[(size_t)(dt * 16) * 2048 + t0 + c * 32];
  };

  auto body = [&](int t, bf16x8 (&KC)[2][4]) {
    const int t0 = t * 64;
    // ---- QK^T (KC = K(t), guaranteed arrived) ----
    f32x4 sc[2][4] = {};
    __builtin_amdgcn_s_setprio(1);
    #pragma unroll
    for (int kk = 0; kk < 2; ++kk)
      #pragma unroll
      for (int kt = 0; kt < 4; ++kt) {
        sc[0][kt] = __builtin_amdgcn_mfma_f32_16x16x32_bf16(KC[kk][kt], qf[0][kk], sc[0][kt], 0, 0, 0);
        sc[1][kt] = __builtin_amdgcn_mfma_f32_16x16x32_bf16(KC[kk][kt], qf[1][kk], sc[1][kt], 0, 0, 0);
      }
    __builtin_amdgcn_s_setprio(0);
    __builtin_amdgcn_sched_barrier(0);
    // ---- KC free: issue K(t+2) into it (2-tile lead) ----
    issueK(KC, (t + 2 < ntiles ? t + 2 : ntiles - 1) * 64);
    __builtin_amdgcn_sched_barrier(0);

    // ---- softmax (pure in-lane steady state) ----
    const bool lastt = (t == ntiles - 1);
    #pragma unroll
    for (int qs = 0; qs < 2; ++qs) {
      const int qrow = q0w + qs * 16 + l15;
      if (lastt) {
        #pragma unroll
        for (int n = 0; n < 4; ++n)
          #pragma unroll
          for (int r = 0; r < 4; ++r)
            if (t0 + n * 16 + lq * 4 + r > qrow) sc[qs][n][r] = -INFINITY;
      }
      float a0 = fmaxf(fmaxf(sc[qs][0][0], sc[qs][0][1]), fmaxf(sc[qs][0][2], sc[qs][0][3]));
      float a1 = fmaxf(fmaxf(sc[qs][1][0], sc[qs][1][1]), fmaxf(sc[qs][1][2], sc[qs][1][3]));
      float a2 = fmaxf(fmaxf(sc[qs][2][0], sc[qs][2][1]), fmaxf(sc[qs][2][2], sc[qs][2][3]));
      float a3 = fmaxf(fmaxf(sc[qs][3][0], sc[qs][3][1]), fmaxf(sc[qs][3][2], sc[qs][3][3]));
      float mx = fmaxf(fmaxf(a0, a1), fmaxf(a2, a3));

      if (__any(mx > m_[qs] + 40.0f)) {        // rare
        float mf = mx;
        mf = fmaxf(mf, __shfl_xor(mf, 16));
        mf = fmaxf(mf, __shfl_xor(mf, 32));
        const float mnew = fmaxf(m_[qs], mf);
        const float alpha = exp2f((m_[qs] - mnew) * SC);
        l_[qs] *= alpha;
        #pragma unroll
        for (int dt = 0; dt < 4; ++dt) accO[qs][dt] *= alpha;
        m_[qs] = mnew;
      }
      const float mS = m_[qs] * SC;
      float s0 = 0.f, s1 = 0.f, s2 = 0.f, s3 = 0.f;
      u64* pp = (u64*)&Ps[qs][l15 * 36 + lq * 2];
      #pragma unroll
      for (int n = 0; n < 4; ++n) {
        float p0 = exp2f(sc[qs][n][0] * SC - mS);
        float p1 = exp2f(sc[qs][n][1] * SC - mS);
        float p2 = exp2f(sc[qs][n][2] * SC - mS);
        float p3 = exp2f(sc[qs][n][3] * SC - mS);
        s0 += p0; s1 += p1; s2 += p2; s3 += p3;
        u32 w0, w1;
        asm("v_cvt_pk_bf16_f32 %0, %1, %2" : "=v"(w0) : "v"(p0), "v"(p1));
        asm("v_cvt_pk_bf16_f32 %0, %1, %2" : "=v"(w1) : "v"(p2), "v"(p3));
        pp[n * 4] = (u64)w0 | ((u64)w1 << 32);
      }
      l_[qs] += (s0 + s1) + (s2 + s3);
    }
    __builtin_amdgcn_sched_barrier(0);
    // ---- V(t) arrival (issued 1 tile ago); K(t+2) keeps flying ----
    asm volatile("s_waitcnt vmcnt(8)" ::: "memory");
    __builtin_amdgcn_sched_barrier(0);

    // ---- PV ----
    __builtin_amdgcn_s_setprio(1);
    #pragma unroll
    for (int qs = 0; qs < 2; ++qs) {
      const u16* p16 = (const u16*)Ps[qs];
      #pragma unroll
      for (int c = 0; c < 2; ++c) {
        bf16x8 b = *(const bf16x8*)&p16[l15 * 72 + c * 32 + lq * 8];
        #pragma unroll
        for (int dt = 0; dt < 4; ++dt)
          accO[qs][dt] = __builtin_amdgcn_mfma_f32_16x16x32_bf16(vf[dt][c], b, accO[qs][dt], 0, 0, 0);
      }
    }
    __builtin_amdgcn_s_setprio(0);
    __builtin_amdgcn_sched_barrier(0);
    // ---- vf free: issue V(t+1) (1-tile lead) ----
    issueV((t + 1 < ntiles ? t + 1 : ntiles - 1) * 64);
    __builtin_amdgcn_sched_barrier(0);
  };

  // prologue: K(0), V(0), K(1) in flight
  issueK(kfA, 0);
  issueV(0);
  issueK(kfB, (ntiles > 1 ? 1 : 0) * 64);

  int t = 0;
  for (; t + 2 <= ntiles; t += 2) {
    body(t, kfA);
    body(t + 1, kfB);
  }
  if (t < ntiles) body(t, kfA);

  #pragma unroll
  for (int qs = 0; qs < 2; ++qs) {
    float lt = l_[qs];
    lt += __shfl_xor(lt, 16);
    lt += __shfl_xor(lt, 32);
    const float rl = 1.0f / lt;
    const int qrow = q0w + qs * 16 + l15;
    #pragma unroll
    for (int dt = 0; dt < 4; ++dt) {
      ushort4 o;
      o.x = f2bf(accO[qs][dt][0] * rl);
      o.y = f2bf(accO[qs][dt][1] * rl);
      o.z = f2bf(accO[qs][dt][2] * rl);
      o.w = f2bf(accO[qs][dt][3] * rl);
      *(ushort4*)&Out[(size_t)qrow * 2048 + qh * 64 + dt * 16 + lq * 4] = o;
    }
  }
}

extern "C" void kernel_launch(void* const* d_in, const int* in_sizes, int n_in,
                              void* d_out, int out_size, void* d_ws, size_t ws_size,
                              hipStream_t stream) {
  const float* x    = (const float*)d_in[0];
  const float* freq = (const float*)d_in[1];
  // d_in[2] = mask (known causal tril; not read)
  const float* wq   = (const float*)d_in[3];
  const float* wk   = (const float*)d_in[4];
  const float* wv   = (const float*)d_in[5];
  const float* wo   = (const float*)d_in[6];
  float* out = (float*)d_out;

  u16* x_bf   = (u16*)d_ws;                       // 2048*2048  (reused as Vt later)
  u16* wqkv_t = x_bf + (size_t)2048 * 2048;       // [3072][2048]
  u16* wo_t   = wqkv_t + (size_t)3072 * 2048;     // [2048][2048]
  u16* y      = wo_t + (size_t)2048 * 2048;       // [2048][3072] = Q | K | V
  u16* attn   = y + (size_t)2048 * 3072;          // [2048][2048]
  u16* vt     = x_bf;                             // [512][2048]  (x_bf dead after QKV GEMM)

  cvt_f32_bf16_k<<<4096, 256, 0, stream>>>(x, x_bf, 2048 * 2048 / 4);
  transpose_cvt_k<<<dim3(64, 64), 256, 0, stream>>>(wq, wqkv_t, 2048, 2048);
  transpose_cvt_k<<<dim3(16, 64), 256, 0, stream>>>(wk, wqkv_t + (size_t)2048 * 2048, 2048, 512);
  transpose_cvt_k<<<dim3(16, 64), 256, 0, stream>>>(wv, wqkv_t + (size_t)2560 * 2048, 2048, 512);
  transpose_cvt_k<<<dim3(64, 64), 256, 0, stream>>>(wo, wo_t, 2048, 2048);

  gemm64_k<u16><<<dim3(24, 32), 256, 0, stream>>>(x_bf, wqkv_t, y, 2048, 3072, 2048);
  rope_k<<<10240, 256, 0, stream>>>(y, freq);
  vtrans_k<<<dim3(32, 8), 256, 0, stream>>>(y, vt);
  attn_k<<<2048, 64, 0, stream>>>(y, vt, attn);
  gemm64_k<float><<<dim3(16, 32), 256, 0, stream>>>(attn, wo_t, out, 2048, 2048, 2048);
}